// Round 1
// baseline (294.702 us; speedup 1.0000x reference)
//
#include <hip/hip_runtime.h>

#define E_DIM 1024
#define NT 16  // K-tiles of BK=64 across E_DIM

typedef __attribute__((ext_vector_type(8))) short bf16x8;
typedef __attribute__((ext_vector_type(4))) float f32x4;
typedef unsigned long long u64;

// ---- monotone float->uint so unsigned min == float min ----
__device__ __forceinline__ unsigned f2mono(float f) {
  unsigned u = __float_as_uint(f);
  return (u & 0x80000000u) ? ~u : (u | 0x80000000u);
}
// pack two fp32 into bf16x2 (truncation) with one v_perm_b32
__device__ __forceinline__ unsigned pk_bf16(float lo, float hi) {
  return __builtin_amdgcn_perm(__float_as_uint(hi), __float_as_uint(lo), 0x07060302u);
}
// async global->LDS, 16B per lane: lds dst is wave-uniform base + lane*16
__device__ __forceinline__ void dma16(const void* g, void* l) {
  __builtin_amdgcn_global_load_lds(
      (const __attribute__((address_space(1))) unsigned*)g,
      (__attribute__((address_space(3))) unsigned*)l, 16, 0, 0);
}
// raw barrier (NO vmcnt drain) + compiler memory fence so LDS ops can't migrate
__device__ __forceinline__ void bar() {
  asm volatile("" ::: "memory");
  __builtin_amdgcn_s_barrier();
  asm volatile("" ::: "memory");
}

// Kernel 1: per-row inverse norms, exact ap_i, init packed min array.
__global__ __launch_bounds__(256) void norms_kernel(
    const float* __restrict__ A, const float* __restrict__ P,
    float* __restrict__ inv_na, float* __restrict__ inv_np,
    float* __restrict__ ap, u64* __restrict__ min64) {
  const int row = blockIdx.x;
  const int t = threadIdx.x;
  const float4* a4 = (const float4*)(A + (size_t)row * E_DIM);
  const float4* p4 = (const float4*)(P + (size_t)row * E_DIM);
  float sa = 0.f, sp = 0.f, sab = 0.f;
  for (int c = t; c < E_DIM / 4; c += 256) {
    float4 a = a4[c];
    float4 p = p4[c];
    sa  += a.x * a.x + a.y * a.y + a.z * a.z + a.w * a.w;
    sp  += p.x * p.x + p.y * p.y + p.z * p.z + p.w * p.w;
    sab += a.x * p.x + a.y * p.y + a.z * p.z + a.w * p.w;
  }
#pragma unroll
  for (int off = 32; off > 0; off >>= 1) {
    sa  += __shfl_down(sa, off);
    sp  += __shfl_down(sp, off);
    sab += __shfl_down(sab, off);
  }
  __shared__ float red[4][3];
  const int wave = t >> 6, lane = t & 63;
  if (lane == 0) { red[wave][0] = sa; red[wave][1] = sp; red[wave][2] = sab; }
  __syncthreads();
  if (t == 0) {
    sa  = red[0][0] + red[1][0] + red[2][0] + red[3][0];
    sp  = red[0][1] + red[1][1] + red[2][1] + red[3][1];
    sab = red[0][2] + red[1][2] + red[2][2] + red[3][2];
    float ina = 1.0f / sqrtf(sa);
    float inp = 1.0f / sqrtf(sp);
    inv_na[row] = ina;
    inv_np[row] = inp;
    ap[row] = sab * ina * inp;
    min64[row] = 0xFFFFFFFFFFFFFFFFULL;  // +max packed
  }
}

// Kernel 1b: fp32 -> bf16 tiled convert for the 256x256/BK=64 GEMM.
// Tile tb = rb*16 + kb covers rows [rb*256,+256) x k [kb*64,+64).
// Within a 32KB tile: shorts[((p*256 + row)*8) + j] where p = kk*4 + q holds
// X[row][kb*64 + kk*32 + q*8 + j] — exact MFMA fragment order, so the GEMM's
// linear global_load_lds staging produces a directly-readable LDS image with
// conflict-free ds_read_b128 (16 lanes -> 256B contiguous).
__global__ __launch_bounds__(256) void convert_kernel(
    const float* __restrict__ A, const float* __restrict__ P,
    unsigned short* __restrict__ At, unsigned short* __restrict__ Pt,
    int ntile) {
  const int b = blockIdx.x;
  const float* X = (b < ntile) ? A : P;
  unsigned short* Xt = (b < ntile) ? At : Pt;
  const int tb = (b < ntile) ? b : b - ntile;
  const int rb = tb >> 4;
  const int kb = tb & 15;
  const int row = threadIdx.x;  // 256 threads = 256 rows
  const float* src = X + (size_t)(rb * 256 + row) * E_DIM + kb * 64;
  unsigned short* dst = Xt + (size_t)tb * 16384;
#pragma unroll
  for (int p = 0; p < 8; ++p) {
    float4 v0 = *(const float4*)(src + p * 8);
    float4 v1 = *(const float4*)(src + p * 8 + 4);
    uint4 o = {pk_bf16(v0.x, v0.y), pk_bf16(v0.z, v0.w),
               pk_bf16(v1.x, v1.y), pk_bf16(v1.z, v1.w)};
    *(uint4*)(dst + ((size_t)p * 256 + row) * 8) = o;
  }
}

// Kernel 2: 256x256-tile bf16 MFMA GEMM dot = A P^T, 8-phase-style schedule.
// 512 threads = 8 waves (2M x 4N), per-wave 128x64 output (8 x 4 fragments),
// BK=64, double-buffered 128KB LDS. Counted vmcnt: tile t+1's 8
// global_load_lds issue at the top of tile t, s_waitcnt vmcnt(8) + raw
// s_barrier — loads stay in flight across all barriers, never drained to 0
// in the main loop. Fragment ds_reads issue one MFMA-cluster ahead;
// s_setprio(1) around each 16-MFMA cluster. Fused min/argmin epilogue.
__global__ __launch_bounds__(512, 2) void simmin_mfma256(
    const unsigned short* __restrict__ At, const unsigned short* __restrict__ Pt,
    const float* __restrict__ inv_np, u64* __restrict__ min64, int nbb) {
  __shared__ __align__(16) short As[2][16384];  // 64KB: 2 x 32KB A-tiles
  __shared__ __align__(16) short Ps[2][16384];  // 64KB: 2 x 32KB P-tiles

  const int lid = blockIdx.x;
  int by, bx;
  if (nbb == 32) {
    // bijective XCD swizzle: 32 supertiles of 4(by) x 8(bx) blocks; the 32
    // co-resident blocks of one XCD form one supertile (4 A-slabs + 8 B-slabs).
    const int xcd = lid & 7;
    const int s = lid >> 3;             // per-XCD sequence [0,128)
    const int g = xcd * 4 + (s >> 5);   // global supertile [0,32)
    const int u = s & 31;
    by = (g >> 2) * 4 + (u >> 3);
    bx = (g & 3) * 8 + (u & 7);
  } else {
    by = lid / nbb;
    bx = lid % nbb;
  }

  const int tid = threadIdx.x;
  const int wave = tid >> 6, lane = tid & 63;
  const int wr = wave >> 2, wc = wave & 3;  // 2 x 4 wave grid
  const int c = lane & 15, q = lane >> 4;

  f32x4 acc[8][4];
#pragma unroll
  for (int mt = 0; mt < 8; ++mt)
#pragma unroll
    for (int nt = 0; nt < 4; ++nt) acc[mt][nt] = (f32x4){0.f, 0.f, 0.f, 0.f};

  const char* Ab = (const char*)At + (size_t)by * (NT * 32768);
  const char* Pb = (const char*)Pt + (size_t)bx * (NT * 32768);
  const int so = wave * 1024 + lane * 16;  // per-lane global offset in 8KB site
  const int lo = wave * 1024;              // wave-uniform LDS offset in site

#define STAGE(kt, bb)                                        \
  do {                                                       \
    const char* ga_ = Ab + (size_t)(kt) * 32768;             \
    const char* gp_ = Pb + (size_t)(kt) * 32768;             \
    char* la_ = ((char*)As) + (bb)*32768;                    \
    char* lp_ = ((char*)Ps) + (bb)*32768;                    \
    _Pragma("unroll") for (int s_ = 0; s_ < 4; ++s_) {       \
      dma16(ga_ + s_ * 8192 + so, la_ + s_ * 8192 + lo);     \
      dma16(gp_ + s_ * 8192 + so, lp_ + s_ * 8192 + lo);     \
    }                                                        \
  } while (0)

  // per-lane fragment bases (shorts) within a tile image
  const int aB = q * 2048 + (wr * 128 + c) * 8;
  const int bB = q * 2048 + (wc * 64 + c) * 8;

  STAGE(0, 0);  // prologue: tile 0 -> buf 0

  for (int t = 0; t < NT; ++t) {
    const int b = t & 1;
    if (t < NT - 1) {
      STAGE(t + 1, b ^ 1);  // WAR-safe: buf b^1 released at t-1's trailing bar
      asm volatile("s_waitcnt vmcnt(8)" ::: "memory");  // tile t landed
    } else {
      asm volatile("s_waitcnt vmcnt(0)" ::: "memory");
    }
    bar();  // B1: tile t visible to all waves

    const short* Abuf = &As[b][0] + aB;
    const short* Bbuf = &Ps[b][0] + bB;

    bf16x8 a0[4][2], a1[4][2], b0[2][2], b1[2][2];
    // pre-reads: A rows mh=0 (8 x b128) + B cols nh=0 (4 x b128)
#pragma unroll
    for (int m = 0; m < 4; ++m)
#pragma unroll
      for (int k = 0; k < 2; ++k)
        a0[m][k] = *(const bf16x8*)(Abuf + k * 8192 + m * 128);
#pragma unroll
    for (int n = 0; n < 2; ++n)
#pragma unroll
      for (int k = 0; k < 2; ++k)
        b0[n][k] = *(const bf16x8*)(Bbuf + k * 8192 + n * 128);
    bar();

    // P0: prefetch B nh=1; MFMA a0 x b0 -> acc[0..3][0..1]
#pragma unroll
    for (int n = 0; n < 2; ++n)
#pragma unroll
      for (int k = 0; k < 2; ++k)
        b1[n][k] = *(const bf16x8*)(Bbuf + k * 8192 + 256 + n * 128);
    __builtin_amdgcn_s_setprio(1);
#pragma unroll
    for (int m = 0; m < 4; ++m)
#pragma unroll
      for (int n = 0; n < 2; ++n)
#pragma unroll
        for (int k = 0; k < 2; ++k)
          acc[m][n] = __builtin_amdgcn_mfma_f32_16x16x32_bf16(
              a0[m][k], b0[n][k], acc[m][n], 0, 0, 0);
    __builtin_amdgcn_s_setprio(0);
    bar();

    // P1: prefetch A mh=1; MFMA a0 x b1 -> acc[0..3][2..3]
#pragma unroll
    for (int m = 0; m < 4; ++m)
#pragma unroll
      for (int k = 0; k < 2; ++k)
        a1[m][k] = *(const bf16x8*)(Abuf + k * 8192 + 512 + m * 128);
    __builtin_amdgcn_s_setprio(1);
#pragma unroll
    for (int m = 0; m < 4; ++m)
#pragma unroll
      for (int n = 0; n < 2; ++n)
#pragma unroll
        for (int k = 0; k < 2; ++k)
          acc[m][2 + n] = __builtin_amdgcn_mfma_f32_16x16x32_bf16(
              a0[m][k], b1[n][k], acc[m][2 + n], 0, 0, 0);
    __builtin_amdgcn_s_setprio(0);
    bar();

    // P2: MFMA a1 x b0 -> acc[4..7][0..1]
    __builtin_amdgcn_s_setprio(1);
#pragma unroll
    for (int m = 0; m < 4; ++m)
#pragma unroll
      for (int n = 0; n < 2; ++n)
#pragma unroll
        for (int k = 0; k < 2; ++k)
          acc[4 + m][n] = __builtin_amdgcn_mfma_f32_16x16x32_bf16(
              a1[m][k], b0[n][k], acc[4 + m][n], 0, 0, 0);
    __builtin_amdgcn_s_setprio(0);
    bar();

    // P3: MFMA a1 x b1 -> acc[4..7][2..3]
    __builtin_amdgcn_s_setprio(1);
#pragma unroll
    for (int m = 0; m < 4; ++m)
#pragma unroll
      for (int n = 0; n < 2; ++n)
#pragma unroll
        for (int k = 0; k < 2; ++k)
          acc[4 + m][2 + n] = __builtin_amdgcn_mfma_f32_16x16x32_bf16(
              a1[m][k], b1[n][k], acc[4 + m][2 + n], 0, 0, 0);
    __builtin_amdgcn_s_setprio(0);
    bar();  // trailing: releases buf b for next iteration's STAGE
  }
#undef STAGE

  // Epilogue. C/D layout: col = lane&15 (=c), row = q*4 + reg.
  float inp_l[4];
#pragma unroll
  for (int nt = 0; nt < 4; ++nt)
    inp_l[nt] = inv_np[bx * 256 + wc * 64 + nt * 16 + c];

  const int rowBase = by * 256 + wr * 128;
#pragma unroll
  for (int mt = 0; mt < 8; ++mt) {
#pragma unroll
    for (int reg = 0; reg < 4; ++reg) {
      const int gi = rowBase + mt * 16 + q * 4 + reg;
      float best = 3.4e38f;
      int bj = 0;
#pragma unroll
      for (int nt = 0; nt < 4; ++nt) {
        const int gj = bx * 256 + wc * 64 + nt * 16 + c;
        float v = acc[mt][nt][reg] * inp_l[nt];
        if (gj != gi && v < best) { best = v; bj = gj; }
      }
#pragma unroll
      for (int off = 1; off < 16; off <<= 1) {
        float ov = __shfl_xor(best, off);
        int oi = __shfl_xor(bj, off);
        if (ov < best) { best = ov; bj = oi; }
      }
      if (c == 0) {
        u64 pk = ((u64)f2mono(best) << 32) | (unsigned)bj;
        atomicMin(&min64[gi], pk);
      }
    }
  }
}

// Fallback GEMM (round-3 proven): fp32 staging + in-loop convert. Used only
// if ws_size can't hold the bf16 pre-converted operands (or B % 256 != 0).
__global__ __launch_bounds__(256) void simmin_mfma(
    const float* __restrict__ A, const float* __restrict__ P,
    const float* __restrict__ inv_np, u64* __restrict__ min64) {
  __shared__ __align__(16) short As[128 * 40];
  __shared__ __align__(16) short Ps[128 * 40];

  const int tid = threadIdx.x;
  const int wave = tid >> 6, lane = tid & 63;
  const int wr = wave >> 1, wc = wave & 1;
  const int rowBase = blockIdx.y * 128;
  const int colBase = blockIdx.x * 128;
  const int c = lane & 15, q = lane >> 4;

  f32x4 acc[4][4];
#pragma unroll
  for (int mt = 0; mt < 4; ++mt)
#pragma unroll
    for (int nt = 0; nt < 4; ++nt) acc[mt][nt] = (f32x4){0.f, 0.f, 0.f, 0.f};

  const int sm = tid >> 1;
  const int sh = (tid & 1) * 16;
  const float* Ab = A + (size_t)(rowBase + sm) * E_DIM + sh;
  const float* Pb = P + (size_t)(colBase + sm) * E_DIM + sh;
  uint4* AsW = (uint4*)&As[sm * 40 + sh];
  uint4* PsW = (uint4*)&Ps[sm * 40 + sh];

  for (int kt = 0; kt < E_DIM; kt += 32) {
    float4 a0 = *(const float4*)(Ab + kt);
    float4 a1 = *(const float4*)(Ab + kt + 4);
    float4 a2 = *(const float4*)(Ab + kt + 8);
    float4 a3 = *(const float4*)(Ab + kt + 12);
    float4 p0 = *(const float4*)(Pb + kt);
    float4 p1 = *(const float4*)(Pb + kt + 4);
    float4 p2 = *(const float4*)(Pb + kt + 8);
    float4 p3 = *(const float4*)(Pb + kt + 12);
    uint4 av0 = {pk_bf16(a0.x, a0.y), pk_bf16(a0.z, a0.w),
                 pk_bf16(a1.x, a1.y), pk_bf16(a1.z, a1.w)};
    uint4 av1 = {pk_bf16(a2.x, a2.y), pk_bf16(a2.z, a2.w),
                 pk_bf16(a3.x, a3.y), pk_bf16(a3.z, a3.w)};
    uint4 pv0 = {pk_bf16(p0.x, p0.y), pk_bf16(p0.z, p0.w),
                 pk_bf16(p1.x, p1.y), pk_bf16(p1.z, p1.w)};
    uint4 pv1 = {pk_bf16(p2.x, p2.y), pk_bf16(p2.z, p2.w),
                 pk_bf16(p3.x, p3.y), pk_bf16(p3.z, p3.w)};
    AsW[0] = av0; AsW[1] = av1;
    PsW[0] = pv0; PsW[1] = pv1;
    __syncthreads();

    bf16x8 af[4], bfr[4];
#pragma unroll
    for (int mt = 0; mt < 4; ++mt)
      af[mt] = *(const bf16x8*)&As[(wr * 64 + mt * 16 + c) * 40 + q * 8];
#pragma unroll
    for (int nt = 0; nt < 4; ++nt)
      bfr[nt] = *(const bf16x8*)&Ps[(wc * 64 + nt * 16 + c) * 40 + q * 8];
#pragma unroll
    for (int mt = 0; mt < 4; ++mt)
#pragma unroll
      for (int nt = 0; nt < 4; ++nt)
        acc[mt][nt] = __builtin_amdgcn_mfma_f32_16x16x32_bf16(
            af[mt], bfr[nt], acc[mt][nt], 0, 0, 0);
    __syncthreads();
  }

  float inp_l[4];
#pragma unroll
  for (int nt = 0; nt < 4; ++nt)
    inp_l[nt] = inv_np[colBase + wc * 64 + nt * 16 + c];

#pragma unroll
  for (int mt = 0; mt < 4; ++mt) {
#pragma unroll
    for (int reg = 0; reg < 4; ++reg) {
      const int gi = rowBase + wr * 64 + mt * 16 + q * 4 + reg;
      float best = 3.4e38f;
      int bidx2 = 0;
#pragma unroll
      for (int nt = 0; nt < 4; ++nt) {
        const int gj = colBase + wc * 64 + nt * 16 + c;
        float v = acc[mt][nt][reg] * inp_l[nt];
        if (gj != gi && v < best) { best = v; bidx2 = gj; }
      }
#pragma unroll
      for (int off = 1; off < 16; off <<= 1) {
        float ov = __shfl_xor(best, off);
        int oi = __shfl_xor(bidx2, off);
        if (ov < best) { best = ov; bidx2 = oi; }
      }
      if (c == 0) {
        u64 pk = ((u64)f2mono(best) << 32) | (unsigned)bidx2;
        atomicMin(&min64[gi], pk);
      }
    }
  }
}

// Kernel 3: exact fp32 recompute of an_i for the selected neighbor.
__global__ __launch_bounds__(256) void an_kernel(
    const float* __restrict__ A, const float* __restrict__ P,
    const float* __restrict__ inv_na, const float* __restrict__ inv_np,
    const u64* __restrict__ min64, float* __restrict__ an, int B) {
  const int row = blockIdx.x;
  const int t = threadIdx.x;
  const unsigned j = (unsigned)(min64[row] & 0xFFFFFFFFULL) & (unsigned)(B - 1);
  const float4* a4 = (const float4*)(A + (size_t)row * E_DIM);
  const float4* p4 = (const float4*)(P + (size_t)j * E_DIM);
  float s = 0.f;
  for (int ci = t; ci < E_DIM / 4; ci += 256) {
    float4 a = a4[ci];
    float4 p = p4[ci];
    s += a.x * p.x + a.y * p.y + a.z * p.z + a.w * p.w;
  }
#pragma unroll
  for (int off = 32; off > 0; off >>= 1) s += __shfl_down(s, off);
  __shared__ float red[4];
  const int wave = t >> 6, lane = t & 63;
  if (lane == 0) red[wave] = s;
  __syncthreads();
  if (t == 0) an[row] = (red[0] + red[1] + red[2] + red[3]) * inv_na[row] * inv_np[j];
}

// Kernel 4: loss_i = relu(1 + ap_i - an_i); out = mean.
__global__ __launch_bounds__(256) void loss_kernel(
    const float* __restrict__ ap, const float* __restrict__ an,
    float* __restrict__ out, int B) {
  const int t = threadIdx.x;
  float s = 0.f;
  for (int i = t; i < B; i += 256) {
    float l = 1.0f + ap[i] - an[i];
    s += (l > 0.f) ? l : 0.f;
  }
#pragma unroll
  for (int off = 32; off > 0; off >>= 1) s += __shfl_down(s, off);
  __shared__ float red[4];
  const int wave = t >> 6, lane = t & 63;
  if (lane == 0) red[wave] = s;
  __syncthreads();
  if (t == 0) out[0] = (red[0] + red[1] + red[2] + red[3]) / (float)B;
}

extern "C" void kernel_launch(void* const* d_in, const int* in_sizes, int n_in,
                              void* d_out, int out_size, void* d_ws, size_t ws_size,
                              hipStream_t stream) {
  const float* A = (const float*)d_in[0];  // anchor  [B][1024] fp32
  const float* P = (const float*)d_in[1];  // positive[B][1024] fp32
  const int B = in_sizes[0] / E_DIM;       // 8192

  const size_t conv_elems = (size_t)B * E_DIM;  // per-matrix bf16 elems
  const size_t need = 2 * conv_elems * 2 + (size_t)B * 24 + 64;

  if (ws_size >= need && (B % 256) == 0) {
    unsigned short* At = (unsigned short*)d_ws;
    unsigned short* Pt = At + conv_elems;
    u64* min64 = (u64*)(Pt + conv_elems);  // 8B-aligned (32MB offset)
    float* inv_na = (float*)(min64 + B);
    float* inv_np = inv_na + B;
    float* ap = inv_np + B;
    float* an = ap + B;
    const int nbb = B / 256;
    const int ntile = nbb * NT;  // tiles per matrix

    norms_kernel<<<B, 256, 0, stream>>>(A, P, inv_na, inv_np, ap, min64);
    convert_kernel<<<2 * ntile, 256, 0, stream>>>(A, P, At, Pt, ntile);
    simmin_mfma256<<<nbb * nbb, 512, 0, stream>>>(At, Pt, inv_np, min64, nbb);
    an_kernel<<<B, 256, 0, stream>>>(A, P, inv_na, inv_np, min64, an, B);
    loss_kernel<<<1, 256, 0, stream>>>(ap, an, (float*)d_out, B);
  } else {
    float* inv_na = (float*)d_ws;
    float* inv_np = inv_na + B;
    float* ap = inv_np + B;
    float* an = ap + B;
    u64* min64 = (u64*)(an + B);
    const int nb = B / 128;
    dim3 grid(nb, nb);

    norms_kernel<<<B, 256, 0, stream>>>(A, P, inv_na, inv_np, ap, min64);
    simmin_mfma<<<grid, 256, 0, stream>>>(A, P, inv_np, min64);
    an_kernel<<<B, 256, 0, stream>>>(A, P, inv_na, inv_np, min64, an, B);
    loss_kernel<<<1, 256, 0, stream>>>(ap, an, (float*)d_out, B);
  }
}

// Round 2
// 288.651 us; speedup vs baseline: 1.0210x; 1.0210x over previous
//
#include <hip/hip_runtime.h>

#define E_DIM 1024
#define NT 16  // K-tiles of BK=64 across E_DIM

typedef __attribute__((ext_vector_type(8))) short bf16x8;
typedef __attribute__((ext_vector_type(4))) float f32x4;
typedef unsigned long long u64;

// ---- monotone float->uint so unsigned min == float min ----
__device__ __forceinline__ unsigned f2mono(float f) {
  unsigned u = __float_as_uint(f);
  return (u & 0x80000000u) ? ~u : (u | 0x80000000u);
}
// pack two fp32 into bf16x2 (truncation) with one v_perm_b32
__device__ __forceinline__ unsigned pk_bf16(float lo, float hi) {
  return __builtin_amdgcn_perm(__float_as_uint(hi), __float_as_uint(lo), 0x07060302u);
}
// async global->LDS, 16B per lane: lds dst is wave-uniform base + lane*16
__device__ __forceinline__ void dma16(const void* g, void* l) {
  __builtin_amdgcn_global_load_lds(
      (const __attribute__((address_space(1))) unsigned*)g,
      (__attribute__((address_space(3))) unsigned*)l, 16, 0, 0);
}
// raw barrier (NO vmcnt drain)
__device__ __forceinline__ void bar() {
  asm volatile("" ::: "memory");
  __builtin_amdgcn_s_barrier();
  asm volatile("" ::: "memory");
}

// Kernel 1: per-row inverse norms, exact ap_i, init packed min array.
__global__ __launch_bounds__(256) void norms_kernel(
    const float* __restrict__ A, const float* __restrict__ P,
    float* __restrict__ inv_na, float* __restrict__ inv_np,
    float* __restrict__ ap, u64* __restrict__ min64) {
  const int row = blockIdx.x;
  const int t = threadIdx.x;
  const float4* a4 = (const float4*)(A + (size_t)row * E_DIM);
  const float4* p4 = (const float4*)(P + (size_t)row * E_DIM);
  float sa = 0.f, sp = 0.f, sab = 0.f;
  for (int c = t; c < E_DIM / 4; c += 256) {
    float4 a = a4[c];
    float4 p = p4[c];
    sa  += a.x * a.x + a.y * a.y + a.z * a.z + a.w * a.w;
    sp  += p.x * p.x + p.y * p.y + p.z * p.z + p.w * p.w;
    sab += a.x * p.x + a.y * p.y + a.z * p.z + a.w * p.w;
  }
#pragma unroll
  for (int off = 32; off > 0; off >>= 1) {
    sa  += __shfl_down(sa, off);
    sp  += __shfl_down(sp, off);
    sab += __shfl_down(sab, off);
  }
  __shared__ float red[4][3];
  const int wave = t >> 6, lane = t & 63;
  if (lane == 0) { red[wave][0] = sa; red[wave][1] = sp; red[wave][2] = sab; }
  __syncthreads();
  if (t == 0) {
    sa  = red[0][0] + red[1][0] + red[2][0] + red[3][0];
    sp  = red[0][1] + red[1][1] + red[2][1] + red[3][1];
    sab = red[0][2] + red[1][2] + red[2][2] + red[3][2];
    float ina = 1.0f / sqrtf(sa);
    float inp = 1.0f / sqrtf(sp);
    inv_na[row] = ina;
    inv_np[row] = inp;
    ap[row] = sab * ina * inp;
    min64[row] = 0xFFFFFFFFFFFFFFFFULL;  // +max packed
  }
}

// Kernel 1b: fp32 -> bf16 tiled convert for the 256x256/BK=64 GEMM.
// Tile tb = rb*16 + kb covers rows [rb*256,+256) x k [kb*64,+64).
// Within a 32KB tile: shorts[((p*256 + row)*8) + j] where p = kk*4 + q holds
// X[row][kb*64 + kk*32 + q*8 + j] — exact MFMA fragment order, so the GEMM's
// linear global_load_lds staging produces a directly-readable LDS image with
// conflict-free ds_read_b128 (16 lanes -> 256B contiguous).
__global__ __launch_bounds__(256) void convert_kernel(
    const float* __restrict__ A, const float* __restrict__ P,
    unsigned short* __restrict__ At, unsigned short* __restrict__ Pt,
    int ntile) {
  const int b = blockIdx.x;
  const float* X = (b < ntile) ? A : P;
  unsigned short* Xt = (b < ntile) ? At : Pt;
  const int tb = (b < ntile) ? b : b - ntile;
  const int rb = tb >> 4;
  const int kb = tb & 15;
  const int row = threadIdx.x;  // 256 threads = 256 rows
  const float* src = X + (size_t)(rb * 256 + row) * E_DIM + kb * 64;
  unsigned short* dst = Xt + (size_t)tb * 16384;
#pragma unroll
  for (int p = 0; p < 8; ++p) {
    float4 v0 = *(const float4*)(src + p * 8);
    float4 v1 = *(const float4*)(src + p * 8 + 4);
    uint4 o = {pk_bf16(v0.x, v0.y), pk_bf16(v0.z, v0.w),
               pk_bf16(v1.x, v1.y), pk_bf16(v1.z, v1.w)};
    *(uint4*)(dst + ((size_t)p * 256 + row) * 8) = o;
  }
}

// Kernel 2: 256x256-tile bf16 MFMA GEMM dot = A P^T.
// 512 threads = 8 waves (2M x 4N), per-wave 128x64 output, BK=64, 128KB
// double-buffered LDS. Balanced 4-phase schedule: every phase pairs ~4-8
// ds_read_b128 issues with a 16-MFMA cluster (LDS pipe ~565-753 cyc vs MFMA
// ~620 cyc per phase per CU — co-busy). Fragment reads issue 1+ phases ahead,
// crossing the tile boundary: P2/P3 prefetch next tile's A0/B0 from the other
// buffer (visibility certified by vmcnt(0)+bar at end of P1; that STAGE was
// issued 2 phases earlier). P2-end bar releases the current buffer, P3 stages
// tile t+2 into it. 3 barriers/tile. Counted vmcnt only (never drains fresh
// loads). Fused per-row min+argmin epilogue.
__global__ __launch_bounds__(512, 2) void simmin_mfma256(
    const unsigned short* __restrict__ At, const unsigned short* __restrict__ Pt,
    const float* __restrict__ inv_np, u64* __restrict__ min64, int nbb) {
  __shared__ __align__(16) short As[2][16384];  // 64KB: 2 x 32KB A-tiles
  __shared__ __align__(16) short Ps[2][16384];  // 64KB: 2 x 32KB P-tiles

  const int lid = blockIdx.x;
  int by, bx;
  if (nbb == 32) {
    // bijective XCD swizzle: 32 supertiles of 4(by) x 8(bx) blocks; the 32
    // co-resident blocks of one XCD form one supertile (4 A-slabs + 8 B-slabs).
    const int xcd = lid & 7;
    const int s = lid >> 3;             // per-XCD sequence [0,128)
    const int g = xcd * 4 + (s >> 5);   // global supertile [0,32)
    const int u = s & 31;
    by = (g >> 2) * 4 + (u >> 3);
    bx = (g & 3) * 8 + (u & 7);
  } else {
    by = lid / nbb;
    bx = lid % nbb;
  }

  const int tid = threadIdx.x;
  const int wave = tid >> 6, lane = tid & 63;
  const int wr = wave >> 2, wc = wave & 3;  // 2 x 4 wave grid
  const int c = lane & 15, q = lane >> 4;

  f32x4 acc[8][4];
#pragma unroll
  for (int mt = 0; mt < 8; ++mt)
#pragma unroll
    for (int nt = 0; nt < 4; ++nt) acc[mt][nt] = (f32x4){0.f, 0.f, 0.f, 0.f};

  const char* Ab_g = (const char*)At + (size_t)by * (NT * 32768);
  const char* Pb_g = (const char*)Pt + (size_t)bx * (NT * 32768);
  const int so = wave * 1024 + lane * 16;  // per-lane global offset in 8KB site
  const int lo = wave * 1024;              // wave-uniform LDS offset in site

  // per-lane fragment bases (shorts) within a tile image
  const int aB = q * 2048 + (wr * 128 + c) * 8;
  const int bB = q * 2048 + (wc * 64 + c) * 8;

#define STAGE(kt, bb)                                              \
  do {                                                             \
    const char* ga_ = Ab_g + (size_t)(kt) * 32768;                 \
    const char* gp_ = Pb_g + (size_t)(kt) * 32768;                 \
    char* la_ = ((char*)As) + (bb) * 32768;                        \
    char* lp_ = ((char*)Ps) + (bb) * 32768;                        \
    _Pragma("unroll") for (int s_ = 0; s_ < 4; ++s_) {             \
      dma16(ga_ + s_ * 8192 + so, la_ + s_ * 8192 + lo);           \
      dma16(gp_ + s_ * 8192 + so, lp_ + s_ * 8192 + lo);           \
    }                                                              \
  } while (0)

#define PHASE_MFMA(ASET, BSET, MB, NB)                                      \
  do {                                                                      \
    __builtin_amdgcn_s_setprio(1);                                          \
    _Pragma("unroll") for (int m_ = 0; m_ < 4; ++m_)                        \
    _Pragma("unroll") for (int n_ = 0; n_ < 2; ++n_)                        \
    _Pragma("unroll") for (int k_ = 0; k_ < 2; ++k_)                        \
      acc[(MB) + m_][(NB) + n_] = __builtin_amdgcn_mfma_f32_16x16x32_bf16(  \
          (ASET)[m_ * 2 + k_], (BSET)[n_ * 2 + k_], acc[(MB) + m_][(NB) + n_], \
          0, 0, 0);                                                         \
    __builtin_amdgcn_s_setprio(0);                                          \
  } while (0)

  // A0r/B0r: current tile's first-half fragments; refilled in-place by P2/P3
  // with the NEXT tile's — no register ping-pong needed.
  bf16x8 A0r[8], B0r[4];

#define BODY(T, CUR, NXT, DO_STAGE)                                         \
  {                                                                         \
    const short* Acur = &As[(CUR)][0] + aB;                                 \
    const short* Bcur = &Ps[(CUR)][0] + bB;                                 \
    const short* Anxt = &As[(NXT)][0] + aB;                                 \
    const short* Bnxt = &Ps[(NXT)][0] + bB;                                 \
    bf16x8 A1[8], B1[4];                                                    \
    /* P0: issue B1 (n2..3, cur); MFMA A0 x B0 */                           \
    _Pragma("unroll") for (int n_ = 0; n_ < 2; ++n_)                        \
    _Pragma("unroll") for (int k_ = 0; k_ < 2; ++k_)                        \
      B1[n_ * 2 + k_] = *(const bf16x8*)(Bcur + k_ * 8192 + 256 + n_ * 128);\
    PHASE_MFMA(A0r, B0r, 0, 0);                                             \
    bar();                                                                  \
    /* P1: issue A1 (m4..7, cur); MFMA A0 x B1; then certify nxt buffer */  \
    _Pragma("unroll") for (int m_ = 0; m_ < 4; ++m_)                        \
    _Pragma("unroll") for (int k_ = 0; k_ < 2; ++k_)                        \
      A1[m_ * 2 + k_] = *(const bf16x8*)(Acur + k_ * 8192 + 512 + m_ * 128);\
    PHASE_MFMA(A0r, B1, 0, 2);                                              \
    asm volatile("s_waitcnt vmcnt(0)" ::: "memory");                        \
    __builtin_amdgcn_s_barrier();                                           \
    __builtin_amdgcn_sched_barrier(0);                                      \
    /* P2: issue next-tile A0 (m0..3, nxt); MFMA A1 x B0 */                 \
    _Pragma("unroll") for (int m_ = 0; m_ < 4; ++m_)                        \
    _Pragma("unroll") for (int k_ = 0; k_ < 2; ++k_)                        \
      A0r[m_ * 2 + k_] = *(const bf16x8*)(Anxt + k_ * 8192 + m_ * 128);     \
    PHASE_MFMA(A1, B0r, 4, 0);                                              \
    bar(); /* all cur reads done in all waves -> cur overwritable */        \
    __builtin_amdgcn_sched_barrier(0);                                      \
    /* P3: STAGE(T+2 -> cur); issue next-tile B0 (nxt); MFMA A1 x B1 */     \
    if (DO_STAGE) STAGE((T) + 2, (CUR));                                    \
    _Pragma("unroll") for (int n_ = 0; n_ < 2; ++n_)                        \
    _Pragma("unroll") for (int k_ = 0; k_ < 2; ++k_)                        \
      B0r[n_ * 2 + k_] = *(const bf16x8*)(Bnxt + k_ * 8192 + n_ * 128);     \
    PHASE_MFMA(A1, B1, 4, 2);                                               \
  }

  // Prologue: stage tiles 0 and 1; certify tile 0; preload A0/B0 fragments.
  STAGE(0, 0);
  STAGE(1, 1);
  asm volatile("s_waitcnt vmcnt(8)" ::: "memory");  // tile 0 landed, tile 1 in flight
  __builtin_amdgcn_s_barrier();
  __builtin_amdgcn_sched_barrier(0);
#pragma unroll
  for (int m_ = 0; m_ < 4; ++m_)
#pragma unroll
    for (int k_ = 0; k_ < 2; ++k_)
      A0r[m_ * 2 + k_] = *(const bf16x8*)(&As[0][0] + aB + k_ * 8192 + m_ * 128);
#pragma unroll
  for (int n_ = 0; n_ < 2; ++n_)
#pragma unroll
    for (int k_ = 0; k_ < 2; ++k_)
      B0r[n_ * 2 + k_] = *(const bf16x8*)(&Ps[0][0] + bB + k_ * 8192 + n_ * 128);

  // Main loop: tiles 0..13 (all STAGE targets t+2 <= 15 valid).
  for (int t = 0; t < NT - 2; ++t) {
    const int cu = t & 1;
    BODY(t, cu, cu ^ 1, true);
  }
  // Tile 14: same body, no stage (t+2 = 16 out of range).
  BODY(NT - 2, 0, 1, false);
  // Tile 15 tail: pure compute, no barriers needed before epilogue.
  {
    const short* Acur = &As[1][0] + aB;
    const short* Bcur = &Ps[1][0] + bB;
    bf16x8 A1[8], B1[4];
#pragma unroll
    for (int n_ = 0; n_ < 2; ++n_)
#pragma unroll
      for (int k_ = 0; k_ < 2; ++k_)
        B1[n_ * 2 + k_] = *(const bf16x8*)(Bcur + k_ * 8192 + 256 + n_ * 128);
    PHASE_MFMA(A0r, B0r, 0, 0);
#pragma unroll
    for (int m_ = 0; m_ < 4; ++m_)
#pragma unroll
      for (int k_ = 0; k_ < 2; ++k_)
        A1[m_ * 2 + k_] = *(const bf16x8*)(Acur + k_ * 8192 + 512 + m_ * 128);
    PHASE_MFMA(A0r, B1, 0, 2);
    PHASE_MFMA(A1, B0r, 4, 0);
    PHASE_MFMA(A1, B1, 4, 2);
  }
#undef BODY
#undef PHASE_MFMA
#undef STAGE

  // Epilogue. C/D layout: col = lane&15 (=c), row = q*4 + reg.
  float inp_l[4];
#pragma unroll
  for (int nt = 0; nt < 4; ++nt)
    inp_l[nt] = inv_np[bx * 256 + wc * 64 + nt * 16 + c];

  const int rowBase = by * 256 + wr * 128;
#pragma unroll
  for (int mt = 0; mt < 8; ++mt) {
#pragma unroll
    for (int reg = 0; reg < 4; ++reg) {
      const int gi = rowBase + mt * 16 + q * 4 + reg;
      float best = 3.4e38f;
      int bj = 0;
#pragma unroll
      for (int nt = 0; nt < 4; ++nt) {
        const int gj = bx * 256 + wc * 64 + nt * 16 + c;
        float v = acc[mt][nt][reg] * inp_l[nt];
        if (gj != gi && v < best) { best = v; bj = gj; }
      }
#pragma unroll
      for (int off = 1; off < 16; off <<= 1) {
        float ov = __shfl_xor(best, off);
        int oi = __shfl_xor(bj, off);
        if (ov < best) { best = ov; bj = oi; }
      }
      if (c == 0) {
        u64 pk = ((u64)f2mono(best) << 32) | (unsigned)bj;
        atomicMin(&min64[gi], pk);
      }
    }
  }
}

// Fallback GEMM (round-3 proven): fp32 staging + in-loop convert. Used only
// if ws_size can't hold the bf16 pre-converted operands (or B % 256 != 0).
__global__ __launch_bounds__(256) void simmin_mfma(
    const float* __restrict__ A, const float* __restrict__ P,
    const float* __restrict__ inv_np, u64* __restrict__ min64) {
  __shared__ __align__(16) short As[128 * 40];
  __shared__ __align__(16) short Ps[128 * 40];

  const int tid = threadIdx.x;
  const int wave = tid >> 6, lane = tid & 63;
  const int wr = wave >> 1, wc = wave & 1;
  const int rowBase = blockIdx.y * 128;
  const int colBase = blockIdx.x * 128;
  const int c = lane & 15, q = lane >> 4;

  f32x4 acc[4][4];
#pragma unroll
  for (int mt = 0; mt < 4; ++mt)
#pragma unroll
    for (int nt = 0; nt < 4; ++nt) acc[mt][nt] = (f32x4){0.f, 0.f, 0.f, 0.f};

  const int sm = tid >> 1;
  const int sh = (tid & 1) * 16;
  const float* Ab = A + (size_t)(rowBase + sm) * E_DIM + sh;
  const float* Pb = P + (size_t)(colBase + sm) * E_DIM + sh;
  uint4* AsW = (uint4*)&As[sm * 40 + sh];
  uint4* PsW = (uint4*)&Ps[sm * 40 + sh];

  for (int kt = 0; kt < E_DIM; kt += 32) {
    float4 a0 = *(const float4*)(Ab + kt);
    float4 a1 = *(const float4*)(Ab + kt + 4);
    float4 a2 = *(const float4*)(Ab + kt + 8);
    float4 a3 = *(const float4*)(Ab + kt + 12);
    float4 p0 = *(const float4*)(Pb + kt);
    float4 p1 = *(const float4*)(Pb + kt + 4);
    float4 p2 = *(const float4*)(Pb + kt + 8);
    float4 p3 = *(const float4*)(Pb + kt + 12);
    uint4 av0 = {pk_bf16(a0.x, a0.y), pk_bf16(a0.z, a0.w),
                 pk_bf16(a1.x, a1.y), pk_bf16(a1.z, a1.w)};
    uint4 av1 = {pk_bf16(a2.x, a2.y), pk_bf16(a2.z, a2.w),
                 pk_bf16(a3.x, a3.y), pk_bf16(a3.z, a3.w)};
    uint4 pv0 = {pk_bf16(p0.x, p0.y), pk_bf16(p0.z, p0.w),
                 pk_bf16(p1.x, p1.y), pk_bf16(p1.z, p1.w)};
    uint4 pv1 = {pk_bf16(p2.x, p2.y), pk_bf16(p2.z, p2.w),
                 pk_bf16(p3.x, p3.y), pk_bf16(p3.z, p3.w)};
    AsW[0] = av0; AsW[1] = av1;
    PsW[0] = pv0; PsW[1] = pv1;
    __syncthreads();

    bf16x8 af[4], bfr[4];
#pragma unroll
    for (int mt = 0; mt < 4; ++mt)
      af[mt] = *(const bf16x8*)&As[(wr * 64 + mt * 16 + c) * 40 + q * 8];
#pragma unroll
    for (int nt = 0; nt < 4; ++nt)
      bfr[nt] = *(const bf16x8*)&Ps[(wc * 64 + nt * 16 + c) * 40 + q * 8];
#pragma unroll
    for (int mt = 0; mt < 4; ++mt)
#pragma unroll
      for (int nt = 0; nt < 4; ++nt)
        acc[mt][nt] = __builtin_amdgcn_mfma_f32_16x16x32_bf16(
            af[mt], bfr[nt], acc[mt][nt], 0, 0, 0);
    __syncthreads();
  }

  float inp_l[4];
#pragma unroll
  for (int nt = 0; nt < 4; ++nt)
    inp_l[nt] = inv_np[colBase + wc * 64 + nt * 16 + c];

#pragma unroll
  for (int mt = 0; mt < 4; ++mt) {
#pragma unroll
    for (int reg = 0; reg < 4; ++reg) {
      const int gi = rowBase + wr * 64 + mt * 16 + q * 4 + reg;
      float best = 3.4e38f;
      int bidx2 = 0;
#pragma unroll
      for (int nt = 0; nt < 4; ++nt) {
        const int gj = colBase + wc * 64 + nt * 16 + c;
        float v = acc[mt][nt][reg] * inp_l[nt];
        if (gj != gi && v < best) { best = v; bidx2 = gj; }
      }
#pragma unroll
      for (int off = 1; off < 16; off <<= 1) {
        float ov = __shfl_xor(best, off);
        int oi = __shfl_xor(bidx2, off);
        if (ov < best) { best = ov; bidx2 = oi; }
      }
      if (c == 0) {
        u64 pk = ((u64)f2mono(best) << 32) | (unsigned)bidx2;
        atomicMin(&min64[gi], pk);
      }
    }
  }
}

// Kernel 3: exact fp32 recompute of an_i for the selected neighbor.
__global__ __launch_bounds__(256) void an_kernel(
    const float* __restrict__ A, const float* __restrict__ P,
    const float* __restrict__ inv_na, const float* __restrict__ inv_np,
    const u64* __restrict__ min64, float* __restrict__ an, int B) {
  const int row = blockIdx.x;
  const int t = threadIdx.x;
  const unsigned j = (unsigned)(min64[row] & 0xFFFFFFFFULL) & (unsigned)(B - 1);
  const float4* a4 = (const float4*)(A + (size_t)row * E_DIM);
  const float4* p4 = (const float4*)(P + (size_t)j * E_DIM);
  float s = 0.f;
  for (int ci = t; ci < E_DIM / 4; ci += 256) {
    float4 a = a4[ci];
    float4 p = p4[ci];
    s += a.x * p.x + a.y * p.y + a.z * p.z + a.w * p.w;
  }
#pragma unroll
  for (int off = 32; off > 0; off >>= 1) s += __shfl_down(s, off);
  __shared__ float red[4];
  const int wave = t >> 6, lane = t & 63;
  if (lane == 0) red[wave] = s;
  __syncthreads();
  if (t == 0) an[row] = (red[0] + red[1] + red[2] + red[3]) * inv_na[row] * inv_np[j];
}

// Kernel 4: loss_i = relu(1 + ap_i - an_i); out = mean.
__global__ __launch_bounds__(256) void loss_kernel(
    const float* __restrict__ ap, const float* __restrict__ an,
    float* __restrict__ out, int B) {
  const int t = threadIdx.x;
  float s = 0.f;
  for (int i = t; i < B; i += 256) {
    float l = 1.0f + ap[i] - an[i];
    s += (l > 0.f) ? l : 0.f;
  }
#pragma unroll
  for (int off = 32; off > 0; off >>= 1) s += __shfl_down(s, off);
  __shared__ float red[4];
  const int wave = t >> 6, lane = t & 63;
  if (lane == 0) red[wave] = s;
  __syncthreads();
  if (t == 0) out[0] = (red[0] + red[1] + red[2] + red[3]) / (float)B;
}

extern "C" void kernel_launch(void* const* d_in, const int* in_sizes, int n_in,
                              void* d_out, int out_size, void* d_ws, size_t ws_size,
                              hipStream_t stream) {
  const float* A = (const float*)d_in[0];  // anchor  [B][1024] fp32
  const float* P = (const float*)d_in[1];  // positive[B][1024] fp32
  const int B = in_sizes[0] / E_DIM;       // 8192

  const size_t conv_elems = (size_t)B * E_DIM;  // per-matrix bf16 elems
  const size_t need = 2 * conv_elems * 2 + (size_t)B * 24 + 64;

  if (ws_size >= need && (B % 256) == 0) {
    unsigned short* At = (unsigned short*)d_ws;
    unsigned short* Pt = At + conv_elems;
    u64* min64 = (u64*)(Pt + conv_elems);  // 8B-aligned (32MB offset)
    float* inv_na = (float*)(min64 + B);
    float* inv_np = inv_na + B;
    float* ap = inv_np + B;
    float* an = ap + B;
    const int nbb = B / 256;
    const int ntile = nbb * NT;  // tiles per matrix

    norms_kernel<<<B, 256, 0, stream>>>(A, P, inv_na, inv_np, ap, min64);
    convert_kernel<<<2 * ntile, 256, 0, stream>>>(A, P, At, Pt, ntile);
    simmin_mfma256<<<nbb * nbb, 512, 0, stream>>>(At, Pt, inv_np, min64, nbb);
    an_kernel<<<B, 256, 0, stream>>>(A, P, inv_na, inv_np, min64, an, B);
    loss_kernel<<<1, 256, 0, stream>>>(ap, an, (float*)d_out, B);
  } else {
    float* inv_na = (float*)d_ws;
    float* inv_np = inv_na + B;
    float* ap = inv_np + B;
    float* an = ap + B;
    u64* min64 = (u64*)(an + B);
    const int nb = B / 128;
    dim3 grid(nb, nb);

    norms_kernel<<<B, 256, 0, stream>>>(A, P, inv_na, inv_np, ap, min64);
    simmin_mfma<<<grid, 256, 0, stream>>>(A, P, inv_np, min64);
    an_kernel<<<B, 256, 0, stream>>>(A, P, inv_na, inv_np, min64, an, B);
    loss_kernel<<<1, 256, 0, stream>>>(ap, an, (float*)d_out, B);
  }
}

// Round 3
// 280.104 us; speedup vs baseline: 1.0521x; 1.0305x over previous
//
#include <hip/hip_runtime.h>

#define E_DIM 1024
#define NT 16  // K-tiles of BK=64 across E_DIM

typedef __attribute__((ext_vector_type(8))) short bf16x8;
typedef __attribute__((ext_vector_type(4))) float f32x4;
typedef unsigned long long u64;

// ---- monotone float->uint so unsigned min == float min ----
__device__ __forceinline__ unsigned f2mono(float f) {
  unsigned u = __float_as_uint(f);
  return (u & 0x80000000u) ? ~u : (u | 0x80000000u);
}
// pack two fp32 into bf16x2 (truncation) with one v_perm_b32
__device__ __forceinline__ unsigned pk_bf16(float lo, float hi) {
  return __builtin_amdgcn_perm(__float_as_uint(hi), __float_as_uint(lo), 0x07060302u);
}
// async global->LDS, 16B per lane: lds dst is wave-uniform base + lane*16
__device__ __forceinline__ void dma16(const void* g, void* l) {
  __builtin_amdgcn_global_load_lds(
      (const __attribute__((address_space(1))) unsigned*)g,
      (__attribute__((address_space(3))) unsigned*)l, 16, 0, 0);
}
// raw barrier (NO vmcnt drain); compiler memory fences pin mem-op order
__device__ __forceinline__ void bar() {
  asm volatile("" ::: "memory");
  __builtin_amdgcn_s_barrier();
  asm volatile("" ::: "memory");
}

// Kernel 1: per-row inverse norms, exact ap_i, init packed min array.
__global__ __launch_bounds__(256) void norms_kernel(
    const float* __restrict__ A, const float* __restrict__ P,
    float* __restrict__ inv_na, float* __restrict__ inv_np,
    float* __restrict__ ap, u64* __restrict__ min64) {
  const int row = blockIdx.x;
  const int t = threadIdx.x;
  const float4* a4 = (const float4*)(A + (size_t)row * E_DIM);
  const float4* p4 = (const float4*)(P + (size_t)row * E_DIM);
  float sa = 0.f, sp = 0.f, sab = 0.f;
  for (int c = t; c < E_DIM / 4; c += 256) {
    float4 a = a4[c];
    float4 p = p4[c];
    sa  += a.x * a.x + a.y * a.y + a.z * a.z + a.w * a.w;
    sp  += p.x * p.x + p.y * p.y + p.z * p.z + p.w * p.w;
    sab += a.x * p.x + a.y * p.y + a.z * p.z + a.w * p.w;
  }
#pragma unroll
  for (int off = 32; off > 0; off >>= 1) {
    sa  += __shfl_down(sa, off);
    sp  += __shfl_down(sp, off);
    sab += __shfl_down(sab, off);
  }
  __shared__ float red[4][3];
  const int wave = t >> 6, lane = t & 63;
  if (lane == 0) { red[wave][0] = sa; red[wave][1] = sp; red[wave][2] = sab; }
  __syncthreads();
  if (t == 0) {
    sa  = red[0][0] + red[1][0] + red[2][0] + red[3][0];
    sp  = red[0][1] + red[1][1] + red[2][1] + red[3][1];
    sab = red[0][2] + red[1][2] + red[2][2] + red[3][2];
    float ina = 1.0f / sqrtf(sa);
    float inp = 1.0f / sqrtf(sp);
    inv_na[row] = ina;
    inv_np[row] = inp;
    ap[row] = sab * ina * inp;
    min64[row] = 0xFFFFFFFFFFFFFFFFULL;  // +max packed
  }
}

// Kernel 1b: fp32 -> bf16 tiled convert, UNIT-MAJOR fragment order.
// Tile tb = rb*16 + kb covers rows [rb*256,+256) x k [kb*64,+64), 32KB.
// Image: shorts[((unit*8 + p)*128 + rr)*8 + j], p = kk*4 + q covering
// k = kb*64 + kk*32 + q*8 + j. Unit split (16KB contiguous halves):
//   A: unit = row>>7           , rr = row&127          (row-halves: wave wr)
//   P: unit = (row>>5)&1       , rr = (row>>6)*32+(row&31)   (nq-halves)
// So the GEMM stages each 16KB unit linearly with global_load_lds and
// ds_read_b128 stays conflict-free (16 lanes -> 256B contiguous).
__global__ __launch_bounds__(256) void convert_kernel(
    const float* __restrict__ A, const float* __restrict__ P,
    unsigned short* __restrict__ At, unsigned short* __restrict__ Pt,
    int ntile) {
  const int b = blockIdx.x;
  const bool isA = (b < ntile);
  const float* X = isA ? A : P;
  unsigned short* Xt = isA ? At : Pt;
  const int tb = isA ? b : b - ntile;
  const int rb = tb >> 4;
  const int kb = tb & 15;
  const int row = threadIdx.x;  // 256 threads = 256 rows
  int unit, rr;
  if (isA) { unit = row >> 7;        rr = row & 127; }
  else     { unit = (row >> 5) & 1;  rr = ((row >> 6) << 5) + (row & 31); }
  const float* src = X + (size_t)(rb * 256 + row) * E_DIM + kb * 64;
  unsigned short* dst = Xt + (size_t)tb * 16384;
#pragma unroll
  for (int p = 0; p < 8; ++p) {
    float4 v0 = *(const float4*)(src + p * 8);
    float4 v1 = *(const float4*)(src + p * 8 + 4);
    uint4 o = {pk_bf16(v0.x, v0.y), pk_bf16(v0.z, v0.w),
               pk_bf16(v1.x, v1.y), pk_bf16(v1.z, v1.w)};
    *(uint4*)(dst + ((size_t)((unit * 8 + p) * 128 + rr)) * 8) = o;
  }
}

// Kernel 2: 256x256-tile bf16 MFMA GEMM dot = A P^T, m201-shape schedule.
// 512 threads = 8 waves (2M x 4N), per-wave 128x64 output, BK=64, 128KB LDS
// (2 slots x 32KB per matrix). Per K-tile: 4 quadrant phases of 16 MFMA.
// Phase = { ds_reads (12/4/8/0) + stage 16KB unit(s) of tile t+1 into the
// other slot -> s_barrier -> lgkmcnt(0) -> setprio(1) 16 MFMA setprio(0)
// -> s_barrier }. Waves pass the post-MFMA barrier right after ISSUING the
// cluster, so next phase's ds_reads overlap the matrix-pipe drain. Counted
// vmcnt only: vmcnt(4) @ ph1-end (certifies current tile's B-nq1, staged 2
// phases ago), vmcnt(2) @ ph4-end (certifies next tile's A+B-nq0, staged
// >=2 phases ago). Never drains fresh loads. Fused min/argmin epilogue.
__global__ __launch_bounds__(512, 2) void simmin_mfma256(
    const unsigned short* __restrict__ At, const unsigned short* __restrict__ Pt,
    const float* __restrict__ inv_np, u64* __restrict__ min64, int nbb) {
  __shared__ __align__(16) short As[2][16384];  // 2 slots x 32KB A-tile
  __shared__ __align__(16) short Ps[2][16384];  // 2 slots x 32KB P-tile

  const int lid = blockIdx.x;
  int by, bx;
  if (nbb == 32) {
    // bijective XCD swizzle: 32 supertiles of 4(by) x 8(bx) blocks.
    const int xcd = lid & 7;
    const int s = lid >> 3;
    const int g = xcd * 4 + (s >> 5);
    const int u = s & 31;
    by = (g >> 2) * 4 + (u >> 3);
    bx = (g & 3) * 8 + (u & 7);
  } else {
    by = lid / nbb;
    bx = lid % nbb;
  }

  const int tid = threadIdx.x;
  const int wave = tid >> 6, lane = tid & 63;
  const int wr = wave >> 2, wc = wave & 3;  // 2 x 4 wave grid
  const int c = lane & 15, q = lane >> 4;

  f32x4 acc[8][4];  // [mq*4+mt][nq*2+nt]
#pragma unroll
  for (int mt = 0; mt < 8; ++mt)
#pragma unroll
    for (int nt = 0; nt < 4; ++nt) acc[mt][nt] = (f32x4){0.f, 0.f, 0.f, 0.f};

  const char* Ab_g = (const char*)At + (size_t)by * (NT * 32768);
  const char* Pb_g = (const char*)Pt + (size_t)bx * (NT * 32768);
  const int so = wave * 1024 + lane * 16;  // per-lane global byte off in unit
  const int lo = wave * 1024;              // wave-uniform LDS byte off in unit

  // LDS short-offsets: + kk*4096 + mq*512 + mt*128 / + nq*8192 + kk*4096 + nt*128
  const int aBase = wr * 8192 + q * 1024 + c * 8;
  const int bBase = q * 1024 + wc * 256 + c * 8;

  char* AsC = (char*)As;
  char* PsC = (char*)Ps;

  // stage one 16KB unit (2 dma16 per wave)
#define DMA_UNIT(GB, LB, kt, u, slot)                                   \
  do {                                                                  \
    const char* g_ = (GB) + (size_t)(kt) * 32768 + (u) * 16384 + so;    \
    char* l_ = (LB) + (slot) * 32768 + (u) * 16384 + lo;                \
    dma16(g_, l_);                                                      \
    dma16(g_ + 8192, l_ + 8192);                                        \
  } while (0)

#define READ_A(MQ, S)                                                       \
  _Pragma("unroll") for (int mt_ = 0; mt_ < 4; ++mt_)                       \
  _Pragma("unroll") for (int kk_ = 0; kk_ < 2; ++kk_)                       \
    Ar[mt_ * 2 + kk_] =                                                     \
        *(const bf16x8*)&As[S][aBase + kk_ * 4096 + (MQ) * 512 + mt_ * 128];

#define READ_B(NQ, DST, S)                                                  \
  _Pragma("unroll") for (int nt_ = 0; nt_ < 2; ++nt_)                       \
  _Pragma("unroll") for (int kk_ = 0; kk_ < 2; ++kk_)                       \
    (DST)[nt_ * 2 + kk_] = *(const bf16x8*)&Ps[S][bBase + (NQ) * 8192 +     \
                                                  kk_ * 4096 + nt_ * 128];

#define MFMA_Q(MQ, NQ, BR)                                                  \
  do {                                                                      \
    __builtin_amdgcn_s_setprio(1);                                          \
    _Pragma("unroll") for (int mt_ = 0; mt_ < 4; ++mt_)                     \
    _Pragma("unroll") for (int nt_ = 0; nt_ < 2; ++nt_)                     \
    _Pragma("unroll") for (int kk_ = 0; kk_ < 2; ++kk_)                     \
      acc[(MQ) * 4 + mt_][(NQ) * 2 + nt_] =                                 \
          __builtin_amdgcn_mfma_f32_16x16x32_bf16(                          \
              Ar[mt_ * 2 + kk_], (BR)[nt_ * 2 + kk_],                       \
              acc[(MQ) * 4 + mt_][(NQ) * 2 + nt_], 0, 0, 0);                \
    __builtin_amdgcn_s_setprio(0);                                          \
  } while (0)

  bf16x8 Ar[8], Br0[4], Br1[4];

  // ---- Prologue: stage tile 0 -> slot 0; certify A + B-nq0 (oldest 6) ----
  DMA_UNIT(Ab_g, AsC, 0, 0, 0);
  DMA_UNIT(Ab_g, AsC, 0, 1, 0);
  DMA_UNIT(Pb_g, PsC, 0, 0, 0);
  DMA_UNIT(Pb_g, PsC, 0, 1, 0);
  asm volatile("s_waitcnt vmcnt(2)" ::: "memory");
  bar();

  // ---- Main loop: tiles 0..14, staging tile t+1 into the other slot ----
  for (int t = 0; t < NT - 1; ++t) {
    const int s = t & 1, ns = s ^ 1;

    // ph1: quadrant (mq0, nq0); stage A(t+1) both units
    READ_A(0, s);
    READ_B(0, Br0, s);
    DMA_UNIT(Ab_g, AsC, t + 1, 0, ns);
    DMA_UNIT(Ab_g, AsC, t + 1, 1, ns);
    bar();
    asm volatile("s_waitcnt lgkmcnt(0)" ::: "memory");
    __builtin_amdgcn_sched_barrier(0);
    MFMA_Q(0, 0, Br0);
    asm volatile("s_waitcnt vmcnt(4)" ::: "memory");  // certify B(t)-nq1
    bar();

    // ph2: quadrant (mq0, nq1); stage B(t+1)-nq0
    READ_B(1, Br1, s);
    DMA_UNIT(Pb_g, PsC, t + 1, 0, ns);
    bar();
    asm volatile("s_waitcnt lgkmcnt(0)" ::: "memory");
    __builtin_amdgcn_sched_barrier(0);
    MFMA_Q(0, 1, Br1);
    bar();

    // ph3: quadrant (mq1, nq1); stage B(t+1)-nq1
    READ_A(1, s);
    DMA_UNIT(Pb_g, PsC, t + 1, 1, ns);
    bar();
    asm volatile("s_waitcnt lgkmcnt(0)" ::: "memory");
    __builtin_amdgcn_sched_barrier(0);
    MFMA_Q(1, 1, Br1);
    bar();

    // ph4: quadrant (mq1, nq0); no reads/stage; certify A(t+1)+B(t+1)-nq0
    MFMA_Q(1, 0, Br0);
    asm volatile("s_waitcnt vmcnt(2)" ::: "memory");
    bar();
  }

  // ---- Tail: tile 15 (slot 1); drain the last unit, then pure compute ----
  asm volatile("s_waitcnt vmcnt(0)" ::: "memory");  // certify B(15)-nq1
  bar();
  READ_A(0, 1);
  READ_B(0, Br0, 1);
  MFMA_Q(0, 0, Br0);
  READ_B(1, Br1, 1);
  MFMA_Q(0, 1, Br1);
  READ_A(1, 1);
  MFMA_Q(1, 1, Br1);
  MFMA_Q(1, 0, Br0);

#undef MFMA_Q
#undef READ_B
#undef READ_A
#undef DMA_UNIT

  // Epilogue. C/D layout: col = lane&15 (=c), row = q*4 + reg.
  // acc index ai = mq*4+mt -> row off (ai>>2)*64 + (ai&3)*16;
  //           ni = nq*2+nt -> col off (ni>>1)*32 + (ni&1)*16.
  float inp_l[4];
#pragma unroll
  for (int ni = 0; ni < 4; ++ni)
    inp_l[ni] =
        inv_np[bx * 256 + wc * 64 + (ni >> 1) * 32 + (ni & 1) * 16 + c];

  const int rowBase = by * 256 + wr * 128;
#pragma unroll
  for (int ai = 0; ai < 8; ++ai) {
    const int mrow = (ai >> 2) * 64 + (ai & 3) * 16;
#pragma unroll
    for (int reg = 0; reg < 4; ++reg) {
      const int gi = rowBase + mrow + q * 4 + reg;
      float best = 3.4e38f;
      int bj = 0;
#pragma unroll
      for (int ni = 0; ni < 4; ++ni) {
        const int gj =
            bx * 256 + wc * 64 + (ni >> 1) * 32 + (ni & 1) * 16 + c;
        float v = acc[ai][ni][reg] * inp_l[ni];
        if (gj != gi && v < best) { best = v; bj = gj; }
      }
#pragma unroll
      for (int off = 1; off < 16; off <<= 1) {
        float ov = __shfl_xor(best, off);
        int oi = __shfl_xor(bj, off);
        if (ov < best) { best = ov; bj = oi; }
      }
      if (c == 0) {
        u64 pk = ((u64)f2mono(best) << 32) | (unsigned)bj;
        atomicMin(&min64[gi], pk);
      }
    }
  }
}

// Fallback GEMM (round-3 proven): fp32 staging + in-loop convert. Used only
// if ws_size can't hold the bf16 pre-converted operands (or B % 256 != 0).
__global__ __launch_bounds__(256) void simmin_mfma(
    const float* __restrict__ A, const float* __restrict__ P,
    const float* __restrict__ inv_np, u64* __restrict__ min64) {
  __shared__ __align__(16) short As[128 * 40];
  __shared__ __align__(16) short Ps[128 * 40];

  const int tid = threadIdx.x;
  const int wave = tid >> 6, lane = tid & 63;
  const int wr = wave >> 1, wc = wave & 1;
  const int rowBase = blockIdx.y * 128;
  const int colBase = blockIdx.x * 128;
  const int c = lane & 15, q = lane >> 4;

  f32x4 acc[4][4];
#pragma unroll
  for (int mt = 0; mt < 4; ++mt)
#pragma unroll
    for (int nt = 0; nt < 4; ++nt) acc[mt][nt] = (f32x4){0.f, 0.f, 0.f, 0.f};

  const int sm = tid >> 1;
  const int sh = (tid & 1) * 16;
  const float* Ab = A + (size_t)(rowBase + sm) * E_DIM + sh;
  const float* Pb = P + (size_t)(colBase + sm) * E_DIM + sh;
  uint4* AsW = (uint4*)&As[sm * 40 + sh];
  uint4* PsW = (uint4*)&Ps[sm * 40 + sh];

  for (int kt = 0; kt < E_DIM; kt += 32) {
    float4 a0 = *(const float4*)(Ab + kt);
    float4 a1 = *(const float4*)(Ab + kt + 4);
    float4 a2 = *(const float4*)(Ab + kt + 8);
    float4 a3 = *(const float4*)(Ab + kt + 12);
    float4 p0 = *(const float4*)(Pb + kt);
    float4 p1 = *(const float4*)(Pb + kt + 4);
    float4 p2 = *(const float4*)(Pb + kt + 8);
    float4 p3 = *(const float4*)(Pb + kt + 12);
    uint4 av0 = {pk_bf16(a0.x, a0.y), pk_bf16(a0.z, a0.w),
                 pk_bf16(a1.x, a1.y), pk_bf16(a1.z, a1.w)};
    uint4 av1 = {pk_bf16(a2.x, a2.y), pk_bf16(a2.z, a2.w),
                 pk_bf16(a3.x, a3.y), pk_bf16(a3.z, a3.w)};
    uint4 pv0 = {pk_bf16(p0.x, p0.y), pk_bf16(p0.z, p0.w),
                 pk_bf16(p1.x, p1.y), pk_bf16(p1.z, p1.w)};
    uint4 pv1 = {pk_bf16(p2.x, p2.y), pk_bf16(p2.z, p2.w),
                 pk_bf16(p3.x, p3.y), pk_bf16(p3.z, p3.w)};
    AsW[0] = av0; AsW[1] = av1;
    PsW[0] = pv0; PsW[1] = pv1;
    __syncthreads();

    bf16x8 af[4], bfr[4];
#pragma unroll
    for (int mt = 0; mt < 4; ++mt)
      af[mt] = *(const bf16x8*)&As[(wr * 64 + mt * 16 + c) * 40 + q * 8];
#pragma unroll
    for (int nt = 0; nt < 4; ++nt)
      bfr[nt] = *(const bf16x8*)&Ps[(wc * 64 + nt * 16 + c) * 40 + q * 8];
#pragma unroll
    for (int mt = 0; mt < 4; ++mt)
#pragma unroll
      for (int nt = 0; nt < 4; ++nt)
        acc[mt][nt] = __builtin_amdgcn_mfma_f32_16x16x32_bf16(
            af[mt], bfr[nt], acc[mt][nt], 0, 0, 0);
    __syncthreads();
  }

  float inp_l[4];
#pragma unroll
  for (int nt = 0; nt < 4; ++nt)
    inp_l[nt] = inv_np[colBase + wc * 64 + nt * 16 + c];

#pragma unroll
  for (int mt = 0; mt < 4; ++mt) {
#pragma unroll
    for (int reg = 0; reg < 4; ++reg) {
      const int gi = rowBase + wr * 64 + mt * 16 + q * 4 + reg;
      float best = 3.4e38f;
      int bidx2 = 0;
#pragma unroll
      for (int nt = 0; nt < 4; ++nt) {
        const int gj = colBase + wc * 64 + nt * 16 + c;
        float v = acc[mt][nt][reg] * inp_l[nt];
        if (gj != gi && v < best) { best = v; bidx2 = gj; }
      }
#pragma unroll
      for (int off = 1; off < 16; off <<= 1) {
        float ov = __shfl_xor(best, off);
        int oi = __shfl_xor(bidx2, off);
        if (ov < best) { best = ov; bidx2 = oi; }
      }
      if (c == 0) {
        u64 pk = ((u64)f2mono(best) << 32) | (unsigned)bidx2;
        atomicMin(&min64[gi], pk);
      }
    }
  }
}

// Kernel 3: exact fp32 recompute of an_i for the selected neighbor.
__global__ __launch_bounds__(256) void an_kernel(
    const float* __restrict__ A, const float* __restrict__ P,
    const float* __restrict__ inv_na, const float* __restrict__ inv_np,
    const u64* __restrict__ min64, float* __restrict__ an, int B) {
  const int row = blockIdx.x;
  const int t = threadIdx.x;
  const unsigned j = (unsigned)(min64[row] & 0xFFFFFFFFULL) & (unsigned)(B - 1);
  const float4* a4 = (const float4*)(A + (size_t)row * E_DIM);
  const float4* p4 = (const float4*)(P + (size_t)j * E_DIM);
  float s = 0.f;
  for (int ci = t; ci < E_DIM / 4; ci += 256) {
    float4 a = a4[ci];
    float4 p = p4[ci];
    s += a.x * p.x + a.y * p.y + a.z * p.z + a.w * p.w;
  }
#pragma unroll
  for (int off = 32; off > 0; off >>= 1) s += __shfl_down(s, off);
  __shared__ float red[4];
  const int wave = t >> 6, lane = t & 63;
  if (lane == 0) red[wave] = s;
  __syncthreads();
  if (t == 0) an[row] = (red[0] + red[1] + red[2] + red[3]) * inv_na[row] * inv_np[j];
}

// Kernel 4: loss_i = relu(1 + ap_i - an_i); out = mean.
__global__ __launch_bounds__(256) void loss_kernel(
    const float* __restrict__ ap, const float* __restrict__ an,
    float* __restrict__ out, int B) {
  const int t = threadIdx.x;
  float s = 0.f;
  for (int i = t; i < B; i += 256) {
    float l = 1.0f + ap[i] - an[i];
    s += (l > 0.f) ? l : 0.f;
  }
#pragma unroll
  for (int off = 32; off > 0; off >>= 1) s += __shfl_down(s, off);
  __shared__ float red[4];
  const int wave = t >> 6, lane = t & 63;
  if (lane == 0) red[wave] = s;
  __syncthreads();
  if (t == 0) out[0] = (red[0] + red[1] + red[2] + red[3]) / (float)B;
}

extern "C" void kernel_launch(void* const* d_in, const int* in_sizes, int n_in,
                              void* d_out, int out_size, void* d_ws, size_t ws_size,
                              hipStream_t stream) {
  const float* A = (const float*)d_in[0];  // anchor  [B][1024] fp32
  const float* P = (const float*)d_in[1];  // positive[B][1024] fp32
  const int B = in_sizes[0] / E_DIM;       // 8192

  const size_t conv_elems = (size_t)B * E_DIM;  // per-matrix bf16 elems
  const size_t need = 2 * conv_elems * 2 + (size_t)B * 24 + 64;

  if (ws_size >= need && (B % 256) == 0) {
    unsigned short* At = (unsigned short*)d_ws;
    unsigned short* Pt = At + conv_elems;
    u64* min64 = (u64*)(Pt + conv_elems);  // 8B-aligned (32MB offset)
    float* inv_na = (float*)(min64 + B);
    float* inv_np = inv_na + B;
    float* ap = inv_np + B;
    float* an = ap + B;
    const int nbb = B / 256;
    const int ntile = nbb * NT;  // tiles per matrix

    norms_kernel<<<B, 256, 0, stream>>>(A, P, inv_na, inv_np, ap, min64);
    convert_kernel<<<2 * ntile, 256, 0, stream>>>(A, P, At, Pt, ntile);
    simmin_mfma256<<<nbb * nbb, 512, 0, stream>>>(At, Pt, inv_np, min64, nbb);
    an_kernel<<<B, 256, 0, stream>>>(A, P, inv_na, inv_np, min64, an, B);
    loss_kernel<<<1, 256, 0, stream>>>(ap, an, (float*)d_out, B);
  } else {
    float* inv_na = (float*)d_ws;
    float* inv_np = inv_na + B;
    float* ap = inv_np + B;
    float* an = ap + B;
    u64* min64 = (u64*)(an + B);
    const int nb = B / 128;
    dim3 grid(nb, nb);

    norms_kernel<<<B, 256, 0, stream>>>(A, P, inv_na, inv_np, ap, min64);
    simmin_mfma<<<grid, 256, 0, stream>>>(A, P, inv_np, min64);
    an_kernel<<<B, 256, 0, stream>>>(A, P, inv_na, inv_np, min64, an, B);
    loss_kernel<<<1, 256, 0, stream>>>(ap, an, (float*)d_out, B);
  }
}

// Round 4
// 279.741 us; speedup vs baseline: 1.0535x; 1.0013x over previous
//
#include <hip/hip_runtime.h>

#define E_DIM 1024
#define NT 16  // K-tiles of BK=64 across E_DIM

typedef __attribute__((ext_vector_type(8))) short bf16x8;
typedef __attribute__((ext_vector_type(4))) float f32x4;
typedef unsigned long long u64;

// ---- monotone float->uint so unsigned min == float min ----
__device__ __forceinline__ unsigned f2mono(float f) {
  unsigned u = __float_as_uint(f);
  return (u & 0x80000000u) ? ~u : (u | 0x80000000u);
}
// pack two fp32 into bf16x2 (truncation) with one v_perm_b32
__device__ __forceinline__ unsigned pk_bf16(float lo, float hi) {
  return __builtin_amdgcn_perm(__float_as_uint(hi), __float_as_uint(lo), 0x07060302u);
}
// async global->LDS, 16B per lane: lds dst is wave-uniform base + lane*16
__device__ __forceinline__ void dma16(const void* g, void* l) {
  __builtin_amdgcn_global_load_lds(
      (const __attribute__((address_space(1))) unsigned*)g,
      (__attribute__((address_space(3))) unsigned*)l, 16, 0, 0);
}
// raw barrier (NO vmcnt drain); compiler memory fences pin mem-op order
__device__ __forceinline__ void bar() {
  asm volatile("" ::: "memory");
  __builtin_amdgcn_s_barrier();
  asm volatile("" ::: "memory");
}

// Kernel 1: per-row inverse norms, exact ap_i, init packed min array.
__global__ __launch_bounds__(256) void norms_kernel(
    const float* __restrict__ A, const float* __restrict__ P,
    float* __restrict__ inv_na, float* __restrict__ inv_np,
    float* __restrict__ ap, u64* __restrict__ min64) {
  const int row = blockIdx.x;
  const int t = threadIdx.x;
  const float4* a4 = (const float4*)(A + (size_t)row * E_DIM);
  const float4* p4 = (const float4*)(P + (size_t)row * E_DIM);
  float sa = 0.f, sp = 0.f, sab = 0.f;
  for (int c = t; c < E_DIM / 4; c += 256) {
    float4 a = a4[c];
    float4 p = p4[c];
    sa  += a.x * a.x + a.y * a.y + a.z * a.z + a.w * a.w;
    sp  += p.x * p.x + p.y * p.y + p.z * p.z + p.w * p.w;
    sab += a.x * p.x + a.y * p.y + a.z * p.z + a.w * p.w;
  }
#pragma unroll
  for (int off = 32; off > 0; off >>= 1) {
    sa  += __shfl_down(sa, off);
    sp  += __shfl_down(sp, off);
    sab += __shfl_down(sab, off);
  }
  __shared__ float red[4][3];
  const int wave = t >> 6, lane = t & 63;
  if (lane == 0) { red[wave][0] = sa; red[wave][1] = sp; red[wave][2] = sab; }
  __syncthreads();
  if (t == 0) {
    sa  = red[0][0] + red[1][0] + red[2][0] + red[3][0];
    sp  = red[0][1] + red[1][1] + red[2][1] + red[3][1];
    sab = red[0][2] + red[1][2] + red[2][2] + red[3][2];
    float ina = 1.0f / sqrtf(sa);
    float inp = 1.0f / sqrtf(sp);
    inv_na[row] = ina;
    inv_np[row] = inp;
    ap[row] = sab * ina * inp;
    min64[row] = 0xFFFFFFFFFFFFFFFFULL;  // +max packed
  }
}

// Kernel 1b: fp32 -> bf16 tiled convert, UNIT-MAJOR fragment order.
// Tile tb = rb*16 + kb covers rows [rb*256,+256) x k [kb*64,+64), 32KB.
// Image: shorts[((unit*8 + p)*128 + rr)*8 + j], p = kk*4 + q covering
// k = kb*64 + kk*32 + q*8 + j. Unit split (16KB contiguous halves):
//   A: unit = row>>7           , rr = row&127          (row-halves: wave wr)
//   P: unit = (row>>5)&1       , rr = (row>>6)*32+(row&31)   (nq-halves)
// So the GEMM stages each 16KB unit linearly with global_load_lds and
// ds_read_b128 stays conflict-free (16 lanes -> 256B contiguous).
__global__ __launch_bounds__(256) void convert_kernel(
    const float* __restrict__ A, const float* __restrict__ P,
    unsigned short* __restrict__ At, unsigned short* __restrict__ Pt,
    int ntile) {
  const int b = blockIdx.x;
  const bool isA = (b < ntile);
  const float* X = isA ? A : P;
  unsigned short* Xt = isA ? At : Pt;
  const int tb = isA ? b : b - ntile;
  const int rb = tb >> 4;
  const int kb = tb & 15;
  const int row = threadIdx.x;  // 256 threads = 256 rows
  int unit, rr;
  if (isA) { unit = row >> 7;        rr = row & 127; }
  else     { unit = (row >> 5) & 1;  rr = ((row >> 6) << 5) + (row & 31); }
  const float* src = X + (size_t)(rb * 256 + row) * E_DIM + kb * 64;
  unsigned short* dst = Xt + (size_t)tb * 16384;
#pragma unroll
  for (int p = 0; p < 8; ++p) {
    float4 v0 = *(const float4*)(src + p * 8);
    float4 v1 = *(const float4*)(src + p * 8 + 4);
    uint4 o = {pk_bf16(v0.x, v0.y), pk_bf16(v0.z, v0.w),
               pk_bf16(v1.x, v1.y), pk_bf16(v1.z, v1.w)};
    *(uint4*)(dst + ((size_t)((unit * 8 + p) * 128 + rr)) * 8) = o;
  }
}

// Kernel 2: 256x256-tile bf16 MFMA GEMM dot = A P^T, barrier-light schedule.
// 512 threads = 8 waves (2M x 4N), per-wave 128x64 output, BK=64, 128KB LDS
// (2 slots x 32KB per matrix). KEY: no intra-tile barriers. All tile-t reads
// hit slot s; all staging writes hit slot ns — so the only cross-wave sync is
// at tile boundaries: lgkmcnt(0)+B1 (all waves done reading ns -> writable),
// STAGE(t+1 -> ns), vmcnt(8) (certify tile-t's 8 dmas WITHOUT draining the 8
// fresh ones), B2 (slot s visible). 2 barriers/tile. The 24-read + 64-MFMA
// tile body is one scheduling region: the compiler's fine-grained lgkmcnt
// interleave overlaps the LDS pipe (~2300 cyc/CU) with the matrix pipe
// (~2480 cyc/CU). Reads placed one quadrant ahead of their consumer.
// Fused per-row min+argmin epilogue.
__global__ __launch_bounds__(512, 2) void simmin_mfma256(
    const unsigned short* __restrict__ At, const unsigned short* __restrict__ Pt,
    const float* __restrict__ inv_np, u64* __restrict__ min64, int nbb) {
  __shared__ __align__(16) short As[2][16384];  // 2 slots x 32KB A-tile
  __shared__ __align__(16) short Ps[2][16384];  // 2 slots x 32KB P-tile

  const int lid = blockIdx.x;
  int by, bx;
  if (nbb == 32) {
    // bijective XCD swizzle: 32 supertiles of 4(by) x 8(bx) blocks.
    const int xcd = lid & 7;
    const int s = lid >> 3;
    const int g = xcd * 4 + (s >> 5);
    const int u = s & 31;
    by = (g >> 2) * 4 + (u >> 3);
    bx = (g & 3) * 8 + (u & 7);
  } else {
    by = lid / nbb;
    bx = lid % nbb;
  }

  const int tid = threadIdx.x;
  const int wave = tid >> 6, lane = tid & 63;
  const int wr = wave >> 2, wc = wave & 3;  // 2 x 4 wave grid
  const int c = lane & 15, q = lane >> 4;

  f32x4 acc[8][4];  // [mq*4+mt][nq*2+nt]
#pragma unroll
  for (int mt = 0; mt < 8; ++mt)
#pragma unroll
    for (int nt = 0; nt < 4; ++nt) acc[mt][nt] = (f32x4){0.f, 0.f, 0.f, 0.f};

  const char* Ab_g = (const char*)At + (size_t)by * (NT * 32768);
  const char* Pb_g = (const char*)Pt + (size_t)bx * (NT * 32768);
  const int so = wave * 1024 + lane * 16;  // per-lane global byte off in unit
  const int lo = wave * 1024;              // wave-uniform LDS byte off in unit

  // LDS short-offsets: + kk*4096 + mq*512 + mt*128 / + nq*8192 + kk*4096 + nt*128
  const int aBase = wr * 8192 + q * 1024 + c * 8;
  const int bBase = q * 1024 + wc * 256 + c * 8;

  char* AsC = (char*)As;
  char* PsC = (char*)Ps;

  // stage one 16KB unit (2 dma16 per wave)
#define DMA_UNIT(GB, LB, kt, u, slot)                                   \
  do {                                                                  \
    const char* g_ = (GB) + (size_t)(kt) * 32768 + (u) * 16384 + so;    \
    char* l_ = (LB) + (slot) * 32768 + (u) * 16384 + lo;                \
    dma16(g_, l_);                                                      \
    dma16(g_ + 8192, l_ + 8192);                                        \
  } while (0)

// stage a full 32KB A-tile + 32KB P-tile (8 dma16 per wave)
#define STAGE(kt, slot)                    \
  do {                                     \
    DMA_UNIT(Ab_g, AsC, kt, 0, slot);      \
    DMA_UNIT(Ab_g, AsC, kt, 1, slot);      \
    DMA_UNIT(Pb_g, PsC, kt, 0, slot);      \
    DMA_UNIT(Pb_g, PsC, kt, 1, slot);      \
  } while (0)

#define READ_A(MQ, S)                                                       \
  _Pragma("unroll") for (int mt_ = 0; mt_ < 4; ++mt_)                       \
  _Pragma("unroll") for (int kk_ = 0; kk_ < 2; ++kk_)                       \
    Ar[mt_ * 2 + kk_] =                                                     \
        *(const bf16x8*)&As[S][aBase + kk_ * 4096 + (MQ) * 512 + mt_ * 128];

#define READ_B(NQ, DST, S)                                                  \
  _Pragma("unroll") for (int nt_ = 0; nt_ < 2; ++nt_)                       \
  _Pragma("unroll") for (int kk_ = 0; kk_ < 2; ++kk_)                       \
    (DST)[nt_ * 2 + kk_] = *(const bf16x8*)&Ps[S][bBase + (NQ) * 8192 +     \
                                                  kk_ * 4096 + nt_ * 128];

#define MFMA_Q(MQ, NQ, BR)                                                  \
  do {                                                                      \
    __builtin_amdgcn_s_setprio(1);                                          \
    _Pragma("unroll") for (int mt_ = 0; mt_ < 4; ++mt_)                     \
    _Pragma("unroll") for (int nt_ = 0; nt_ < 2; ++nt_)                     \
    _Pragma("unroll") for (int kk_ = 0; kk_ < 2; ++kk_)                     \
      acc[(MQ) * 4 + mt_][(NQ) * 2 + nt_] =                                 \
          __builtin_amdgcn_mfma_f32_16x16x32_bf16(                          \
              Ar[mt_ * 2 + kk_], (BR)[nt_ * 2 + kk_],                       \
              acc[(MQ) * 4 + mt_][(NQ) * 2 + nt_], 0, 0, 0);                \
    __builtin_amdgcn_s_setprio(0);                                          \
  } while (0)

  bf16x8 Ar[8], Br0[4], Br1[4];

  // ---- Prologue: stage tile 0 -> slot 0 ----
  STAGE(0, 0);  // 8 outstanding

  // ---- Main loop: one boundary (2 barriers) + one free-scheduled body ----
  for (int t = 0; t < NT; ++t) {
    const int s = t & 1, ns = s ^ 1;

    // Boundary: free ns (WAR), stage t+1 into it, certify tile t in s.
    asm volatile("s_waitcnt lgkmcnt(0)" ::: "memory");  // own reads of ns done
    bar();                                              // B1: ns writable
    if (t + 1 < NT) {
      STAGE(t + 1, ns);                                 // outstanding = old + 8
      asm volatile("s_waitcnt vmcnt(8)" ::: "memory");  // tile t's 8 landed
    } else {
      asm volatile("s_waitcnt vmcnt(0)" ::: "memory");  // last tile: drain
    }
    bar();  // B2: slot s visible to all waves

    // Tile body: no barriers; compiler interleaves ds_read drain with MFMA.
    READ_A(0, s);        // 8 reads -> Ar (A-mq0)
    READ_B(0, Br0, s);   // 4 reads
    MFMA_Q(0, 0, Br0);
    READ_B(1, Br1, s);   // 4 reads (overlap Q00 drain)
    MFMA_Q(0, 1, Br1);
    READ_A(1, s);        // 8 reads -> Ar (A-mq1; overlaps Q01 drain)
    MFMA_Q(1, 0, Br0);
    MFMA_Q(1, 1, Br1);
  }

#undef MFMA_Q
#undef READ_B
#undef READ_A
#undef STAGE
#undef DMA_UNIT

  // Epilogue. C/D layout: col = lane&15 (=c), row = q*4 + reg.
  // acc index ai = mq*4+mt -> row off (ai>>2)*64 + (ai&3)*16;
  //           ni = nq*2+nt -> col off (ni>>1)*32 + (ni&1)*16.
  float inp_l[4];
#pragma unroll
  for (int ni = 0; ni < 4; ++ni)
    inp_l[ni] =
        inv_np[bx * 256 + wc * 64 + (ni >> 1) * 32 + (ni & 1) * 16 + c];

  const int rowBase = by * 256 + wr * 128;
#pragma unroll
  for (int ai = 0; ai < 8; ++ai) {
    const int mrow = (ai >> 2) * 64 + (ai & 3) * 16;
#pragma unroll
    for (int reg = 0; reg < 4; ++reg) {
      const int gi = rowBase + mrow + q * 4 + reg;
      float best = 3.4e38f;
      int bj = 0;
#pragma unroll
      for (int ni = 0; ni < 4; ++ni) {
        const int gj =
            bx * 256 + wc * 64 + (ni >> 1) * 32 + (ni & 1) * 16 + c;
        float v = acc[ai][ni][reg] * inp_l[ni];
        if (gj != gi && v < best) { best = v; bj = gj; }
      }
#pragma unroll
      for (int off = 1; off < 16; off <<= 1) {
        float ov = __shfl_xor(best, off);
        int oi = __shfl_xor(bj, off);
        if (ov < best) { best = ov; bj = oi; }
      }
      if (c == 0) {
        u64 pk = ((u64)f2mono(best) << 32) | (unsigned)bj;
        atomicMin(&min64[gi], pk);
      }
    }
  }
}

// Fallback GEMM (round-3 proven): fp32 staging + in-loop convert. Used only
// if ws_size can't hold the bf16 pre-converted operands (or B % 256 != 0).
__global__ __launch_bounds__(256) void simmin_mfma(
    const float* __restrict__ A, const float* __restrict__ P,
    const float* __restrict__ inv_np, u64* __restrict__ min64) {
  __shared__ __align__(16) short As[128 * 40];
  __shared__ __align__(16) short Ps[128 * 40];

  const int tid = threadIdx.x;
  const int wave = tid >> 6, lane = tid & 63;
  const int wr = wave >> 1, wc = wave & 1;
  const int rowBase = blockIdx.y * 128;
  const int colBase = blockIdx.x * 128;
  const int c = lane & 15, q = lane >> 4;

  f32x4 acc[4][4];
#pragma unroll
  for (int mt = 0; mt < 4; ++mt)
#pragma unroll
    for (int nt = 0; nt < 4; ++nt) acc[mt][nt] = (f32x4){0.f, 0.f, 0.f, 0.f};

  const int sm = tid >> 1;
  const int sh = (tid & 1) * 16;
  const float* Ab = A + (size_t)(rowBase + sm) * E_DIM + sh;
  const float* Pb = P + (size_t)(colBase + sm) * E_DIM + sh;
  uint4* AsW = (uint4*)&As[sm * 40 + sh];
  uint4* PsW = (uint4*)&Ps[sm * 40 + sh];

  for (int kt = 0; kt < E_DIM; kt += 32) {
    float4 a0 = *(const float4*)(Ab + kt);
    float4 a1 = *(const float4*)(Ab + kt + 4);
    float4 a2 = *(const float4*)(Ab + kt + 8);
    float4 a3 = *(const float4*)(Ab + kt + 12);
    float4 p0 = *(const float4*)(Pb + kt);
    float4 p1 = *(const float4*)(Pb + kt + 4);
    float4 p2 = *(const float4*)(Pb + kt + 8);
    float4 p3 = *(const float4*)(Pb + kt + 12);
    uint4 av0 = {pk_bf16(a0.x, a0.y), pk_bf16(a0.z, a0.w),
                 pk_bf16(a1.x, a1.y), pk_bf16(a1.z, a1.w)};
    uint4 av1 = {pk_bf16(a2.x, a2.y), pk_bf16(a2.z, a2.w),
                 pk_bf16(a3.x, a3.y), pk_bf16(a3.z, a3.w)};
    uint4 pv0 = {pk_bf16(p0.x, p0.y), pk_bf16(p0.z, p0.w),
                 pk_bf16(p1.x, p1.y), pk_bf16(p1.z, p1.w)};
    uint4 pv1 = {pk_bf16(p2.x, p2.y), pk_bf16(p2.z, p2.w),
                 pk_bf16(p3.x, p3.y), pk_bf16(p3.z, p3.w)};
    AsW[0] = av0; AsW[1] = av1;
    PsW[0] = pv0; PsW[1] = pv1;
    __syncthreads();

    bf16x8 af[4], bfr[4];
#pragma unroll
    for (int mt = 0; mt < 4; ++mt)
      af[mt] = *(const bf16x8*)&As[(wr * 64 + mt * 16 + c) * 40 + q * 8];
#pragma unroll
    for (int nt = 0; nt < 4; ++nt)
      bfr[nt] = *(const bf16x8*)&Ps[(wc * 64 + nt * 16 + c) * 40 + q * 8];
#pragma unroll
    for (int mt = 0; mt < 4; ++mt)
#pragma unroll
      for (int nt = 0; nt < 4; ++nt)
        acc[mt][nt] = __builtin_amdgcn_mfma_f32_16x16x32_bf16(
            af[mt], bfr[nt], acc[mt][nt], 0, 0, 0);
    __syncthreads();
  }

  float inp_l[4];
#pragma unroll
  for (int nt = 0; nt < 4; ++nt)
    inp_l[nt] = inv_np[colBase + wc * 64 + nt * 16 + c];

#pragma unroll
  for (int mt = 0; mt < 4; ++mt) {
#pragma unroll
    for (int reg = 0; reg < 4; ++reg) {
      const int gi = rowBase + wr * 64 + mt * 16 + q * 4 + reg;
      float best = 3.4e38f;
      int bidx2 = 0;
#pragma unroll
      for (int nt = 0; nt < 4; ++nt) {
        const int gj = colBase + wc * 64 + nt * 16 + c;
        float v = acc[mt][nt][reg] * inp_l[nt];
        if (gj != gi && v < best) { best = v; bidx2 = gj; }
      }
#pragma unroll
      for (int off = 1; off < 16; off <<= 1) {
        float ov = __shfl_xor(best, off);
        int oi = __shfl_xor(bidx2, off);
        if (ov < best) { best = ov; bidx2 = oi; }
      }
      if (c == 0) {
        u64 pk = ((u64)f2mono(best) << 32) | (unsigned)bidx2;
        atomicMin(&min64[gi], pk);
      }
    }
  }
}

// Kernel 3: exact fp32 recompute of an_i for the selected neighbor.
__global__ __launch_bounds__(256) void an_kernel(
    const float* __restrict__ A, const float* __restrict__ P,
    const float* __restrict__ inv_na, const float* __restrict__ inv_np,
    const u64* __restrict__ min64, float* __restrict__ an, int B) {
  const int row = blockIdx.x;
  const int t = threadIdx.x;
  const unsigned j = (unsigned)(min64[row] & 0xFFFFFFFFULL) & (unsigned)(B - 1);
  const float4* a4 = (const float4*)(A + (size_t)row * E_DIM);
  const float4* p4 = (const float4*)(P + (size_t)j * E_DIM);
  float s = 0.f;
  for (int ci = t; ci < E_DIM / 4; ci += 256) {
    float4 a = a4[ci];
    float4 p = p4[ci];
    s += a.x * p.x + a.y * p.y + a.z * p.z + a.w * p.w;
  }
#pragma unroll
  for (int off = 32; off > 0; off >>= 1) s += __shfl_down(s, off);
  __shared__ float red[4];
  const int wave = t >> 6, lane = t & 63;
  if (lane == 0) red[wave] = s;
  __syncthreads();
  if (t == 0) an[row] = (red[0] + red[1] + red[2] + red[3]) * inv_na[row] * inv_np[j];
}

// Kernel 4: loss_i = relu(1 + ap_i - an_i); out = mean.
__global__ __launch_bounds__(256) void loss_kernel(
    const float* __restrict__ ap, const float* __restrict__ an,
    float* __restrict__ out, int B) {
  const int t = threadIdx.x;
  float s = 0.f;
  for (int i = t; i < B; i += 256) {
    float l = 1.0f + ap[i] - an[i];
    s += (l > 0.f) ? l : 0.f;
  }
#pragma unroll
  for (int off = 32; off > 0; off >>= 1) s += __shfl_down(s, off);
  __shared__ float red[4];
  const int wave = t >> 6, lane = t & 63;
  if (lane == 0) red[wave] = s;
  __syncthreads();
  if (t == 0) out[0] = (red[0] + red[1] + red[2] + red[3]) / (float)B;
}

extern "C" void kernel_launch(void* const* d_in, const int* in_sizes, int n_in,
                              void* d_out, int out_size, void* d_ws, size_t ws_size,
                              hipStream_t stream) {
  const float* A = (const float*)d_in[0];  // anchor  [B][1024] fp32
  const float* P = (const float*)d_in[1];  // positive[B][1024] fp32
  const int B = in_sizes[0] / E_DIM;       // 8192

  const size_t conv_elems = (size_t)B * E_DIM;  // per-matrix bf16 elems
  const size_t need = 2 * conv_elems * 2 + (size_t)B * 24 + 64;

  if (ws_size >= need && (B % 256) == 0) {
    unsigned short* At = (unsigned short*)d_ws;
    unsigned short* Pt = At + conv_elems;
    u64* min64 = (u64*)(Pt + conv_elems);  // 8B-aligned (32MB offset)
    float* inv_na = (float*)(min64 + B);
    float* inv_np = inv_na + B;
    float* ap = inv_np + B;
    float* an = ap + B;
    const int nbb = B / 256;
    const int ntile = nbb * NT;  // tiles per matrix

    norms_kernel<<<B, 256, 0, stream>>>(A, P, inv_na, inv_np, ap, min64);
    convert_kernel<<<2 * ntile, 256, 0, stream>>>(A, P, At, Pt, ntile);
    simmin_mfma256<<<nbb * nbb, 512, 0, stream>>>(At, Pt, inv_np, min64, nbb);
    an_kernel<<<B, 256, 0, stream>>>(A, P, inv_na, inv_np, min64, an, B);
    loss_kernel<<<1, 256, 0, stream>>>(ap, an, (float*)d_out, B);
  } else {
    float* inv_na = (float*)d_ws;
    float* inv_np = inv_na + B;
    float* ap = inv_np + B;
    float* an = ap + B;
    u64* min64 = (u64*)(an + B);
    const int nb = B / 128;
    dim3 grid(nb, nb);

    norms_kernel<<<B, 256, 0, stream>>>(A, P, inv_na, inv_np, ap, min64);
    simmin_mfma<<<grid, 256, 0, stream>>>(A, P, inv_np, min64);
    an_kernel<<<B, 256, 0, stream>>>(A, P, inv_na, inv_np, min64, an, B);
    loss_kernel<<<1, 256, 0, stream>>>(ap, an, (float*)d_out, B);
  }
}